// Round 1
// baseline (490.929 us; speedup 1.0000x reference)
//
#include <hip/hip_runtime.h>

// OHEM BCE-with-logits loss, MI355X.
// logits: (B, 2, H, W) f32, we use channel 1 only. target: (B, H, W) f32 in {0,1}.
// Output: scalar f32 = mean(pos bce) + mean(top-k neg bce), k = min(num_neg, 20*num_pos).
// Key insight: neg bce = softplus(x) is monotonic in x -> radix-select on float bits of x.

#define HW_SHIFT 20                 // H*W = 1<<20 (1024*1024), fixed by the problem
#define HW_MASK  ((1 << HW_SHIFT) - 1)

struct ScalarWs {
  unsigned numPos;
  unsigned p12;      // selected top-12-bit key bucket
  unsigned rank;     // residual rank within bucket (1-based)
  unsigned k;
  unsigned cntHigh;  // unused sanity slot
  unsigned pad;
  double posSum;     // sum softplus(-x) over positives (pos_weight applied at the end)
  double sumHigh;    // sum softplus(x) over negatives with keytop > p12
};

__device__ __forceinline__ float softplusf(float x) {
  // jax.nn.softplus: max(x,0) + log1p(exp(-|x|))
  return fmaxf(x, 0.0f) + log1pf(expf(-fabsf(x)));
}

__device__ __forceinline__ unsigned keymap(float x) {
  // monotonic map: u ascending <=> x ascending
  unsigned b = __float_as_uint(x);
  unsigned m = (unsigned)((int)b >> 31);
  return b ^ (m | 0x80000000u);
}

// ---------------- Pass 1: pos stats + 12-bit key histogram over negatives ----
__global__ void __launch_bounds__(256) p1_kernel(
    const float* __restrict__ logits, const float* __restrict__ target,
    unsigned* __restrict__ ghist, ScalarWs* __restrict__ sc, int nGroups) {
  __shared__ unsigned hist[4096];
  for (int i = threadIdx.x; i < 4096; i += 256) hist[i] = 0;
  __syncthreads();

  unsigned posCnt = 0;
  float posSum = 0.0f;
  int idx = blockIdx.x * 256 + threadIdx.x;
  int stride = gridDim.x * 256;
  for (int g = idx; g < nGroups; g += stride) {
    int base = g << 2;
    int b = base >> HW_SHIFT;
    int inner = base & HW_MASK;
    const float4 xv = *reinterpret_cast<const float4*>(
        logits + (((size_t)b) << (HW_SHIFT + 1)) + (1u << HW_SHIFT) + inner);
    const float4 tv = *reinterpret_cast<const float4*>(target + base);
    const float xs[4] = {xv.x, xv.y, xv.z, xv.w};
    const float ts[4] = {tv.x, tv.y, tv.z, tv.w};
#pragma unroll
    for (int j = 0; j < 4; ++j) {
      float x = xs[j];
      if (ts[j] > 0.5f) {
        posCnt++;
        posSum += softplusf(-x);
      } else {
        atomicAdd(&hist[keymap(x) >> 20], 1u);
      }
    }
  }
  __syncthreads();
  for (int i = threadIdx.x; i < 4096; i += 256) {
    unsigned v = hist[i];
    if (v) atomicAdd(&ghist[i], v);
  }
  // wave-level reduce of pos stats, one atomic per wave
#pragma unroll
  for (int o = 32; o; o >>= 1) {
    posCnt += __shfl_down(posCnt, o, 64);
    posSum += __shfl_down(posSum, o, 64);
  }
  if ((threadIdx.x & 63) == 0) {
    if (posCnt) atomicAdd(&sc->numPos, posCnt);
    atomicAdd(&sc->posSum, (double)posSum);
  }
}

// ---------------- S1: find 12-bit bucket of the k-th largest ----------------
__global__ void __launch_bounds__(256) s1_kernel(
    const unsigned* __restrict__ ghist, ScalarWs* __restrict__ sc, int nTotal) {
  int tid = threadIdx.x;
  unsigned vals[16];
  unsigned mySum = 0;
#pragma unroll
  for (int j = 0; j < 16; ++j) {
    vals[j] = ghist[tid * 16 + j];
    mySum += vals[j];
  }
  __shared__ unsigned chunk[256];
  chunk[tid] = mySum;
  __syncthreads();
  unsigned cumAbove = 0;
  for (int j = tid + 1; j < 256; ++j) cumAbove += chunk[j];

  unsigned numPos = sc->numPos;
  unsigned numNeg = (unsigned)nTotal - numPos;
  unsigned k = (numPos > 0) ? min(numNeg, 20u * numPos)
                            : max(1u, numNeg / 100u);
  if (numNeg == 0) k = 0;
  if (tid == 0) sc->k = k;
  if (k == 0) {
    if (tid == 0) { sc->p12 = 0; sc->rank = 0; }
    return;
  }
  if (cumAbove < k && k <= cumAbove + mySum) {
    unsigned c = cumAbove;
#pragma unroll
    for (int j = 15; j >= 0; --j) {
      if (c + vals[j] >= k) {
        sc->p12 = (unsigned)(tid * 16 + j);
        sc->rank = k - c;
        break;
      }
      c += vals[j];
    }
  }
}

// ---------------- Pass 2: high sums + 12-bit refinement within bucket -------
__global__ void __launch_bounds__(256) p2_kernel(
    const float* __restrict__ logits, const float* __restrict__ target,
    unsigned* __restrict__ gcnt2, float* __restrict__ gsum2,
    ScalarWs* __restrict__ sc, int nGroups) {
  __shared__ unsigned cnt2[4096];
  __shared__ float sum2[4096];
  for (int i = threadIdx.x; i < 4096; i += 256) { cnt2[i] = 0; sum2[i] = 0.0f; }
  const unsigned p12 = sc->p12;
  __syncthreads();

  unsigned cntHigh = 0;
  float sumHigh = 0.0f;
  int idx = blockIdx.x * 256 + threadIdx.x;
  int stride = gridDim.x * 256;
  for (int g = idx; g < nGroups; g += stride) {
    int base = g << 2;
    int b = base >> HW_SHIFT;
    int inner = base & HW_MASK;
    const float4 xv = *reinterpret_cast<const float4*>(
        logits + (((size_t)b) << (HW_SHIFT + 1)) + (1u << HW_SHIFT) + inner);
    const float4 tv = *reinterpret_cast<const float4*>(target + base);
    const float xs[4] = {xv.x, xv.y, xv.z, xv.w};
    const float ts[4] = {tv.x, tv.y, tv.z, tv.w};
#pragma unroll
    for (int j = 0; j < 4; ++j) {
      float x = xs[j];
      if (!(ts[j] > 0.5f)) {
        unsigned u = keymap(x);
        unsigned top = u >> 20;
        if (top > p12) {
          cntHigh++;
          sumHigh += softplusf(x);
        } else if (top == p12) {
          unsigned mid = (u >> 8) & 0xFFFu;
          atomicAdd(&cnt2[mid], 1u);
          atomicAdd(&sum2[mid], softplusf(x));
        }
      }
    }
  }
  __syncthreads();
  for (int i = threadIdx.x; i < 4096; i += 256) {
    unsigned c = cnt2[i];
    if (c) {
      atomicAdd(&gcnt2[i], c);
      atomicAdd(&gsum2[i], sum2[i]);
    }
  }
#pragma unroll
  for (int o = 32; o; o >>= 1) {
    cntHigh += __shfl_down(cntHigh, o, 64);
    sumHigh += __shfl_down(sumHigh, o, 64);
  }
  if ((threadIdx.x & 63) == 0) {
    if (cntHigh) atomicAdd(&sc->cntHigh, cntHigh);
    atomicAdd(&sc->sumHigh, (double)sumHigh);
  }
}

// ---------------- S2: finalize ----------------------------------------------
__global__ void __launch_bounds__(256) s2_kernel(
    const unsigned* __restrict__ gcnt2, const float* __restrict__ gsum2,
    ScalarWs* __restrict__ sc, const float* __restrict__ pwPtr,
    float* __restrict__ out) {
  int tid = threadIdx.x;
  unsigned cvals[16];
  double svals[16];
  unsigned cSum = 0;
  double sSum = 0.0;
#pragma unroll
  for (int j = 0; j < 16; ++j) {
    cvals[j] = gcnt2[tid * 16 + j];
    svals[j] = (double)gsum2[tid * 16 + j];
    cSum += cvals[j];
    sSum += svals[j];
  }
  __shared__ unsigned cChunk[256];
  __shared__ double sChunk[256];
  cChunk[tid] = cSum;
  sChunk[tid] = sSum;
  __syncthreads();
  unsigned cumAboveC = 0;
  double cumAboveS = 0.0;
  for (int j = tid + 1; j < 256; ++j) {
    cumAboveC += cChunk[j];
    cumAboveS += sChunk[j];
  }

  unsigned k = sc->k;
  unsigned r = sc->rank;
  unsigned numPos = sc->numPos;
  double posKeep = (numPos > 0) ? ((double)pwPtr[0] * sc->posSum / (double)numPos) : 0.0;

  if (k == 0) {
    if (tid == 0) out[0] = (float)posKeep;
    return;
  }
  if (cumAboveC < r && r <= cumAboveC + cSum) {
    unsigned c = cumAboveC;
    double s = cumAboveS;
#pragma unroll
    for (int j = 15; j >= 0; --j) {
      if (c + cvals[j] >= r) {
        unsigned r2 = r - c;
        double mean = svals[j] / (double)cvals[j];
        double negSum = sc->sumHigh + s + (double)r2 * mean;
        double negKeep = negSum / (double)k;
        out[0] = (float)(posKeep + negKeep);
        break;
      }
      c += cvals[j];
      s += svals[j];
    }
  }
}

extern "C" void kernel_launch(void* const* d_in, const int* in_sizes, int n_in,
                              void* d_out, int out_size, void* d_ws, size_t ws_size,
                              hipStream_t stream) {
  const float* logits = (const float*)d_in[0];
  const float* target = (const float*)d_in[1];
  const float* pw = (const float*)d_in[2];
  float* out = (float*)d_out;

  int nTotal = in_sizes[1];     // B*H*W (33,554,432)
  int nGroups = nTotal >> 2;

  char* ws = (char*)d_ws;
  unsigned* ghist = (unsigned*)ws;               // 4096 * 4B
  unsigned* gcnt2 = (unsigned*)(ws + 16384);     // 4096 * 4B
  float* gsum2 = (float*)(ws + 32768);           // 4096 * 4B
  ScalarWs* sc = (ScalarWs*)(ws + 49152);

  hipMemsetAsync(d_ws, 0, 49152 + sizeof(ScalarWs), stream);

  p1_kernel<<<2048, 256, 0, stream>>>(logits, target, ghist, sc, nGroups);
  s1_kernel<<<1, 256, 0, stream>>>(ghist, sc, nTotal);
  p2_kernel<<<2048, 256, 0, stream>>>(logits, target, gcnt2, gsum2, sc, nGroups);
  s2_kernel<<<1, 256, 0, stream>>>(gcnt2, gsum2, sc, pw, out);
}

// Round 2
// 457.327 us; speedup vs baseline: 1.0735x; 1.0735x over previous
//
#include <hip/hip_runtime.h>

// OHEM BCE-with-logits loss, MI355X.
// logits: (B, 2, H, W) f32, channel 1 only. target: (B, H, W) f32 in {0,1}.
// out scalar = mean(pos bce) + mean(top-k neg bce), k = min(num_neg, 20*num_pos).
// neg bce = softplus(x) monotonic in x -> radix-select on monotonic float-key bits.

#define HW_SHIFT 20                 // H*W = 1<<20, fixed by the problem
#define HW_MASK  ((1 << HW_SHIFT) - 1)

struct ScalarWs {
  unsigned numPos;
  unsigned p12;      // selected top-12-bit key bucket
  unsigned rank;     // residual rank within bucket (1-based)
  unsigned k;
  unsigned cntHigh;
  unsigned pad;
  double posSum;     // sum softplus(-x) over positives
  double sumHigh;    // sum softplus(x) over negatives with keytop > p12
};

// fast softplus: hardware v_exp_f32 / v_log_f32. abs err ~1e-6, threshold 5.8e-2.
__device__ __forceinline__ float softplus_fast(float x) {
  return fmaxf(x, 0.0f) + __logf(1.0f + __expf(-fabsf(x)));
}

__device__ __forceinline__ unsigned keymap(float x) {
  unsigned b = __float_as_uint(x);
  unsigned m = (unsigned)((int)b >> 31);
  return b ^ (m | 0x80000000u);   // monotonic: u ascending <=> x ascending
}

// ---------------- Pass 1: pos stats + 12-bit key histogram + pos bitmask ----
template <bool WRITE_MASK>
__global__ void __launch_bounds__(256) p1_kernel(
    const float* __restrict__ logits, const float* __restrict__ target,
    unsigned* __restrict__ ghist, ScalarWs* __restrict__ sc,
    ulonglong4* __restrict__ masks, int nGroups) {
  __shared__ unsigned hist[4097];   // [4096] = trash bin for positives
  for (int i = threadIdx.x; i < 4097; i += 256) hist[i] = 0;
  __syncthreads();

  const int lane = threadIdx.x & 63;
  const int idx = blockIdx.x * 256 + threadIdx.x;
  const int stride = gridDim.x * 256;          // 524288: stride*4 % (1<<HW_SHIFT) == 0
  const int e0 = idx << 2;
  const int b0 = e0 >> HW_SHIFT;
  const int inner = e0 & HW_MASK;
  const float* lp = logits + (((size_t)b0) << (HW_SHIFT + 1)) + (1u << HW_SHIFT) + inner;
  const float* tp = target + (((size_t)b0) << HW_SHIFT) + inner;
  const size_t tAdv = (size_t)stride << 2;                                   // floats
  const size_t lAdv = (size_t)(stride >> (HW_SHIFT - 2)) << (HW_SHIFT + 1);  // floats
  int mIdx = idx >> 6;
  const int mAdv = stride >> 6;

  unsigned posCnt = 0;
  float posSum = 0.0f;
  for (int g = idx; g < nGroups; g += stride) {
    const float4 xv = *reinterpret_cast<const float4*>(lp);
    const float4 tv = *reinterpret_cast<const float4*>(tp);
    const float xs[4] = {xv.x, xv.y, xv.z, xv.w};
    const float ts[4] = {tv.x, tv.y, tv.z, tv.w};
    unsigned long long mj[4];
#pragma unroll
    for (int j = 0; j < 4; ++j) {
      float x = xs[j], t = ts[j];        // t is exactly 0.0f or 1.0f
      bool pos = t > 0.5f;
      posSum = __builtin_fmaf(t, softplus_fast(-x), posSum);
      posCnt += pos ? 1u : 0u;
      unsigned bin = pos ? 4096u : (keymap(x) >> 20);
      atomicAdd(&hist[bin], 1u);         // unconditional ds_add, no divergence
      if (WRITE_MASK) mj[j] = __ballot(pos);
    }
    if (WRITE_MASK && lane == 0)
      masks[mIdx] = make_ulonglong4(mj[0], mj[1], mj[2], mj[3]);
    mIdx += mAdv;
    lp += lAdv;
    tp += tAdv;
  }
  __syncthreads();
  for (int i = threadIdx.x; i < 4096; i += 256) {
    unsigned v = hist[i];
    if (v) atomicAdd(&ghist[i], v);
  }
#pragma unroll
  for (int o = 32; o; o >>= 1) {
    posCnt += __shfl_down(posCnt, o, 64);
    posSum += __shfl_down(posSum, o, 64);
  }
  if (lane == 0) {
    if (posCnt) atomicAdd(&sc->numPos, posCnt);
    atomicAdd(&sc->posSum, (double)posSum);
  }
}

// ---------------- S1: find 12-bit bucket of the k-th largest ----------------
__global__ void __launch_bounds__(256) s1_kernel(
    const unsigned* __restrict__ ghist, ScalarWs* __restrict__ sc, int nTotal) {
  int tid = threadIdx.x;
  unsigned vals[16];
  unsigned mySum = 0;
#pragma unroll
  for (int j = 0; j < 16; ++j) {
    vals[j] = ghist[tid * 16 + j];
    mySum += vals[j];
  }
  __shared__ unsigned chunk[256];
  chunk[tid] = mySum;
  __syncthreads();
  unsigned cumAbove = 0;
  for (int j = tid + 1; j < 256; ++j) cumAbove += chunk[j];

  unsigned numPos = sc->numPos;
  unsigned numNeg = (unsigned)nTotal - numPos;
  unsigned k = (numPos > 0) ? min(numNeg, 20u * numPos) : max(1u, numNeg / 100u);
  if (numNeg == 0) k = 0;
  if (tid == 0) sc->k = k;
  if (k == 0) {
    if (tid == 0) { sc->p12 = 0; sc->rank = 0; }
    return;
  }
  if (cumAbove < k && k <= cumAbove + mySum) {
    unsigned c = cumAbove;
#pragma unroll
    for (int j = 15; j >= 0; --j) {
      if (c + vals[j] >= k) {
        sc->p12 = (unsigned)(tid * 16 + j);
        sc->rank = k - c;
        break;
      }
      c += vals[j];
    }
  }
}

// ---------------- Pass 2: high sums + 12-bit refinement within bucket -------
template <bool USE_MASK>
__global__ void __launch_bounds__(256) p2_kernel(
    const float* __restrict__ logits, const float* __restrict__ target,
    const ulonglong4* __restrict__ masks,
    unsigned* __restrict__ gcnt2, float* __restrict__ gsum2,
    ScalarWs* __restrict__ sc, int nGroups) {
  __shared__ unsigned cnt2[4096];
  __shared__ float sum2[4096];
  for (int i = threadIdx.x; i < 4096; i += 256) { cnt2[i] = 0; sum2[i] = 0.0f; }
  const unsigned p12 = sc->p12;
  __syncthreads();

  const int lane = threadIdx.x & 63;
  const int idx = blockIdx.x * 256 + threadIdx.x;
  const int stride = gridDim.x * 256;
  const int e0 = idx << 2;
  const int b0 = e0 >> HW_SHIFT;
  const int inner = e0 & HW_MASK;
  const float* lp = logits + (((size_t)b0) << (HW_SHIFT + 1)) + (1u << HW_SHIFT) + inner;
  const float* tp = target + (((size_t)b0) << HW_SHIFT) + inner;
  const size_t tAdv = (size_t)stride << 2;
  const size_t lAdv = (size_t)(stride >> (HW_SHIFT - 2)) << (HW_SHIFT + 1);
  int mIdx = idx >> 6;
  const int mAdv = stride >> 6;

  unsigned cntHigh = 0;
  float sumHigh = 0.0f;
  for (int g = idx; g < nGroups; g += stride) {
    const float4 xv = *reinterpret_cast<const float4*>(lp);
    const float xs[4] = {xv.x, xv.y, xv.z, xv.w};
    bool neg[4];
    if (USE_MASK) {
      const ulonglong4 mm = masks[mIdx];   // wave-uniform 32B load
      neg[0] = !((mm.x >> lane) & 1ull);
      neg[1] = !((mm.y >> lane) & 1ull);
      neg[2] = !((mm.z >> lane) & 1ull);
      neg[3] = !((mm.w >> lane) & 1ull);
    } else {
      const float4 tv = *reinterpret_cast<const float4*>(tp);
      neg[0] = !(tv.x > 0.5f);
      neg[1] = !(tv.y > 0.5f);
      neg[2] = !(tv.z > 0.5f);
      neg[3] = !(tv.w > 0.5f);
    }
#pragma unroll
    for (int j = 0; j < 4; ++j) {
      float x = xs[j];
      unsigned u = keymap(x);
      unsigned top = u >> 20;
      float sp = softplus_fast(x);
      bool hi = neg[j] && (top > p12);
      cntHigh += hi ? 1u : 0u;
      sumHigh += hi ? sp : 0.0f;
      bool inB = neg[j] && (top == p12);
      if (inB) {                            // rare: ~1/4096 of elements
        unsigned mid = (u >> 8) & 0xFFFu;
        atomicAdd(&cnt2[mid], 1u);
        atomicAdd(&sum2[mid], sp);
      }
    }
    mIdx += mAdv;
    lp += lAdv;
    tp += tAdv;
  }
  __syncthreads();
  for (int i = threadIdx.x; i < 4096; i += 256) {
    unsigned c = cnt2[i];
    if (c) {
      atomicAdd(&gcnt2[i], c);
      atomicAdd(&gsum2[i], sum2[i]);
    }
  }
#pragma unroll
  for (int o = 32; o; o >>= 1) {
    cntHigh += __shfl_down(cntHigh, o, 64);
    sumHigh += __shfl_down(sumHigh, o, 64);
  }
  if (lane == 0) {
    if (cntHigh) atomicAdd(&sc->cntHigh, cntHigh);
    atomicAdd(&sc->sumHigh, (double)sumHigh);
  }
}

// ---------------- S2: finalize ----------------------------------------------
__global__ void __launch_bounds__(256) s2_kernel(
    const unsigned* __restrict__ gcnt2, const float* __restrict__ gsum2,
    ScalarWs* __restrict__ sc, const float* __restrict__ pwPtr,
    float* __restrict__ out) {
  int tid = threadIdx.x;
  unsigned cvals[16];
  double svals[16];
  unsigned cSum = 0;
  double sSum = 0.0;
#pragma unroll
  for (int j = 0; j < 16; ++j) {
    cvals[j] = gcnt2[tid * 16 + j];
    svals[j] = (double)gsum2[tid * 16 + j];
    cSum += cvals[j];
    sSum += svals[j];
  }
  __shared__ unsigned cChunk[256];
  __shared__ double sChunk[256];
  cChunk[tid] = cSum;
  sChunk[tid] = sSum;
  __syncthreads();
  unsigned cumAboveC = 0;
  double cumAboveS = 0.0;
  for (int j = tid + 1; j < 256; ++j) {
    cumAboveC += cChunk[j];
    cumAboveS += sChunk[j];
  }

  unsigned k = sc->k;
  unsigned r = sc->rank;
  unsigned numPos = sc->numPos;
  double posKeep = (numPos > 0) ? ((double)pwPtr[0] * sc->posSum / (double)numPos) : 0.0;

  if (k == 0) {
    if (tid == 0) out[0] = (float)posKeep;
    return;
  }
  if (cumAboveC < r && r <= cumAboveC + cSum) {
    unsigned c = cumAboveC;
    double s = cumAboveS;
#pragma unroll
    for (int j = 15; j >= 0; --j) {
      if (c + cvals[j] >= r) {
        unsigned r2 = r - c;
        double mean = svals[j] / (double)cvals[j];
        double negSum = sc->sumHigh + s + (double)r2 * mean;
        out[0] = (float)(posKeep + negSum / (double)k);
        break;
      }
      c += cvals[j];
      s += svals[j];
    }
  }
}

extern "C" void kernel_launch(void* const* d_in, const int* in_sizes, int n_in,
                              void* d_out, int out_size, void* d_ws, size_t ws_size,
                              hipStream_t stream) {
  const float* logits = (const float*)d_in[0];
  const float* target = (const float*)d_in[1];
  const float* pw = (const float*)d_in[2];
  float* out = (float*)d_out;

  int nTotal = in_sizes[1];     // B*H*W
  int nGroups = nTotal >> 2;

  char* ws = (char*)d_ws;
  unsigned* ghist = (unsigned*)ws;               // 4096 * 4B
  unsigned* gcnt2 = (unsigned*)(ws + 16384);     // 4096 * 4B
  float* gsum2 = (float*)(ws + 32768);           // 4096 * 4B
  ScalarWs* sc = (ScalarWs*)(ws + 49152);
  ulonglong4* masks = (ulonglong4*)(ws + 65536); // 1 bit/element = nTotal/8 bytes

  size_t maskBytes = (size_t)(nGroups >> 6) * sizeof(ulonglong4);
  bool useMask = ((nGroups & 63) == 0) && (ws_size >= 65536 + maskBytes);

  hipMemsetAsync(d_ws, 0, 49152 + sizeof(ScalarWs), stream);

  if (useMask) {
    p1_kernel<true><<<2048, 256, 0, stream>>>(logits, target, ghist, sc, masks, nGroups);
    s1_kernel<<<1, 256, 0, stream>>>(ghist, sc, nTotal);
    p2_kernel<true><<<2048, 256, 0, stream>>>(logits, target, masks, gcnt2, gsum2, sc, nGroups);
  } else {
    p1_kernel<false><<<2048, 256, 0, stream>>>(logits, target, ghist, sc, masks, nGroups);
    s1_kernel<<<1, 256, 0, stream>>>(ghist, sc, nTotal);
    p2_kernel<false><<<2048, 256, 0, stream>>>(logits, target, masks, gcnt2, gsum2, sc, nGroups);
  }
  s2_kernel<<<1, 256, 0, stream>>>(gcnt2, gsum2, sc, pw, out);
}

// Round 3
// 79.254 us; speedup vs baseline: 6.1943x; 5.7704x over previous
//
#include <hip/hip_runtime.h>

// OHEM BCE-with-logits loss, MI355X — single-pass histogram design.
// logits: (B, 2, H, W) f32, channel 1 only. target: (B, H, W) f32 in {0,1}.
// out scalar = mean(pos bce) + mean(top-k neg bce), k = min(num_neg, 20*num_pos).
// neg bce = softplus(x), monotonic in x -> rank-select on 12-bit monotonic key;
// within the cut bin use bin-mean (bin width <= 2^-3 relative -> error ~2e-4,
// threshold 5.8e-2). Per-bin {count, sum} in ONE pass; no contended atomics:
// pos stats via per-block plain stores, hist via 8 XCD-split copies + rotation.

#define HW_SHIFT 20                 // H*W = 1<<20, fixed by the problem
#define HW_MASK  ((1 << HW_SHIFT) - 1)
#define NBINS 4096
#define NCOPY 8
#define NBLK 1024
#define SCALE 16384.0f              // 2^14 fixed-point for softplus sums
#define INV_SCALE (1.0 / 16384.0)

// fast softplus: hardware v_exp_f32 / v_log_f32. abs err ~1e-6.
__device__ __forceinline__ float softplus_fast(float x) {
  return fmaxf(x, 0.0f) + __logf(1.0f + __expf(-fabsf(x)));
}

__device__ __forceinline__ unsigned keymap(float x) {
  unsigned b = __float_as_uint(x);
  unsigned m = (unsigned)((int)b >> 31);
  return b ^ (m | 0x80000000u);   // monotonic: u ascending <=> x ascending
}

// ---------------- Pass 1: everything streamed once --------------------------
__global__ void __launch_bounds__(256) p1_kernel(
    const float* __restrict__ logits, const float* __restrict__ target,
    unsigned long long* __restrict__ gsum,   // [NCOPY][NBINS] scaled sums
    unsigned* __restrict__ ghist,            // [NCOPY][NBINS] counts
    unsigned* __restrict__ pcnt,             // [NBLK] per-block pos count
    double* __restrict__ psum,               // [NBLK] per-block pos sum
    int nGroups) {
  __shared__ unsigned long long lhist[NBINS + 1];   // [NBINS] = trash (positives)
  for (int i = threadIdx.x; i < NBINS + 1; i += 256) lhist[i] = 0ull;
  __syncthreads();

  const int lane = threadIdx.x & 63;
  const int wid = threadIdx.x >> 6;
  const int idx = blockIdx.x * 256 + threadIdx.x;
  const int stride = gridDim.x * 256;   // 262144 threads; stride*4 == 1<<HW_SHIFT
  const int e0 = idx << 2;
  const int b0 = e0 >> HW_SHIFT;
  const int inner = e0 & HW_MASK;
  const float* lp = logits + (((size_t)b0) << (HW_SHIFT + 1)) + (1u << HW_SHIFT) + inner;
  const float* tp = target + (((size_t)b0) << HW_SHIFT) + inner;
  const size_t tAdv = (size_t)stride << 2;                                   // floats
  const size_t lAdv = (size_t)(stride >> (HW_SHIFT - 2)) << (HW_SHIFT + 1);  // floats

  unsigned posCnt = 0;
  float posSum = 0.0f;
  for (int g = idx; g < nGroups; g += stride) {
    const float4 xv = *reinterpret_cast<const float4*>(lp);
    const float4 tv = *reinterpret_cast<const float4*>(tp);
    const float xs[4] = {xv.x, xv.y, xv.z, xv.w};
    const float ts[4] = {tv.x, tv.y, tv.z, tv.w};
#pragma unroll
    for (int j = 0; j < 4; ++j) {
      const float x = xs[j], t = ts[j];   // t is exactly 0.0f or 1.0f
      const bool pos = t > 0.5f;
      const float sp = softplus_fast(x);
      // softplus(-x) = softplus(x) - x
      posSum = __builtin_fmaf(t, sp - x, posSum);
      posCnt += pos ? 1u : 0u;
      const unsigned bin = pos ? (unsigned)NBINS : (keymap(x) >> 20);
      const unsigned su = (unsigned)__builtin_fmaf(sp, SCALE, 0.5f);
      atomicAdd(&lhist[bin], 0x0001000000000000ull | (unsigned long long)su);
    }
    lp += lAdv;
    tp += tAdv;
  }
  __syncthreads();

  // flush: rotated bin order + XCD-split copy -> short, decorrelated chains
  const unsigned copy = blockIdx.x & (NCOPY - 1);
  unsigned long long* gs = gsum + (size_t)copy * NBINS;
  unsigned* gh = ghist + (size_t)copy * NBINS;
  const unsigned rot = (unsigned)(blockIdx.x << 6);
  for (int i = threadIdx.x; i < NBINS; i += 256) {
    const unsigned b = (i + rot) & (NBINS - 1);
    const unsigned long long v = lhist[b];
    if (v) {
      atomicAdd(&gh[b], (unsigned)(v >> 48));
      atomicAdd(&gs[b], v & 0x0000FFFFFFFFFFFFull);
    }
  }

  // per-block pos stats -> plain stores (no global atomics)
#pragma unroll
  for (int o = 32; o; o >>= 1) {
    posCnt += __shfl_down(posCnt, o, 64);
    posSum += __shfl_down(posSum, o, 64);
  }
  __shared__ unsigned wpc[4];
  __shared__ float wps[4];
  if (lane == 0) { wpc[wid] = posCnt; wps[wid] = posSum; }
  __syncthreads();
  if (threadIdx.x == 0) {
    pcnt[blockIdx.x] = wpc[0] + wpc[1] + wpc[2] + wpc[3];
    psum[blockIdx.x] = (double)wps[0] + (double)wps[1] + (double)wps[2] + (double)wps[3];
  }
}

// ---------------- S1: reduce + select + finalize ----------------------------
__global__ void __launch_bounds__(256) s1_kernel(
    const unsigned long long* __restrict__ gsum, const unsigned* __restrict__ ghist,
    const unsigned* __restrict__ pcnt, const double* __restrict__ psum,
    const float* __restrict__ pwPtr, float* __restrict__ out, int nTotal) {
  const int tid = threadIdx.x;

  // reduce per-block pos partials
  unsigned pc = 0;
  double ps = 0.0;
  for (int i = tid; i < NBLK; i += 256) { pc += pcnt[i]; ps += psum[i]; }
  __shared__ unsigned spc[256];
  __shared__ double sps[256];
  spc[tid] = pc; sps[tid] = ps;
  __syncthreads();
  for (int o = 128; o; o >>= 1) {
    if (tid < o) { spc[tid] += spc[tid + o]; sps[tid] += sps[tid + o]; }
    __syncthreads();
  }
  const unsigned numPos = spc[0];
  const double posSum = sps[0];
  __syncthreads();

  // reduce the NCOPY histogram copies; per-thread 16 bins
  unsigned cv[16];
  double sv[16];
  unsigned cS = 0;
  double sS = 0.0;
#pragma unroll
  for (int j = 0; j < 16; ++j) {
    const int bin = tid * 16 + j;
    unsigned c = 0;
    unsigned long long s = 0ull;
#pragma unroll
    for (int cp = 0; cp < NCOPY; ++cp) {
      c += ghist[cp * NBINS + bin];
      s += gsum[cp * NBINS + bin];
    }
    cv[j] = c;
    sv[j] = (double)s * INV_SCALE;
    cS += c;
    sS += sv[j];
  }
  __shared__ unsigned cChunk[256];
  __shared__ double sChunk[256];
  cChunk[tid] = cS; sChunk[tid] = sS;
  __syncthreads();
  unsigned cumAboveC = 0;
  double cumAboveS = 0.0;
  for (int j = tid + 1; j < 256; ++j) {
    cumAboveC += cChunk[j];
    cumAboveS += sChunk[j];
  }

  const unsigned numNeg = (unsigned)nTotal - numPos;
  unsigned k = (numPos > 0) ? min(numNeg, 20u * numPos) : max(1u, numNeg / 100u);
  if (numNeg == 0) k = 0;
  const double posKeep = (numPos > 0) ? ((double)pwPtr[0] * posSum / (double)numPos) : 0.0;
  if (k == 0) {
    if (tid == 0) out[0] = (float)posKeep;
    return;
  }
  // exactly one thread holds the rank boundary
  if (cumAboveC < k && k <= cumAboveC + cS) {
    unsigned c = cumAboveC;
    double s = cumAboveS;
#pragma unroll
    for (int j = 15; j >= 0; --j) {
      if (c + cv[j] >= k) {
        const unsigned r2 = k - c;
        const double mean = sv[j] / (double)cv[j];
        const double negSum = s + (double)r2 * mean;
        out[0] = (float)(posKeep + negSum / (double)k);
        break;
      }
      c += cv[j];
      s += sv[j];
    }
  }
}

extern "C" void kernel_launch(void* const* d_in, const int* in_sizes, int n_in,
                              void* d_out, int out_size, void* d_ws, size_t ws_size,
                              hipStream_t stream) {
  const float* logits = (const float*)d_in[0];
  const float* target = (const float*)d_in[1];
  const float* pw = (const float*)d_in[2];
  float* out = (float*)d_out;

  const int nTotal = in_sizes[1];     // B*H*W
  const int nGroups = nTotal >> 2;

  char* ws = (char*)d_ws;
  unsigned long long* gsum = (unsigned long long*)ws;        // NCOPY*NBINS*8 = 256 KiB
  unsigned* ghist = (unsigned*)(ws + 262144);                // NCOPY*NBINS*4 = 128 KiB
  unsigned* pcnt = (unsigned*)(ws + 393216);                 // NBLK*4 = 4 KiB
  double* psum = (double*)(ws + 397312);                     // NBLK*8 = 8 KiB

  hipMemsetAsync(d_ws, 0, 393216, stream);
  p1_kernel<<<NBLK, 256, 0, stream>>>(logits, target, gsum, ghist, pcnt, psum, nGroups);
  s1_kernel<<<1, 256, 0, stream>>>(gsum, ghist, pcnt, psum, pw, out, nTotal);
}